// Round 18
// baseline (261.686 us; speedup 1.0000x reference)
//
#include <hip/hip_runtime.h>
#include <stdint.h>

#define ROWS 150528              // 1024 * 147
#define QSCALE 0.17677669529663687f
#define L2E 1.44269504088896f

typedef __attribute__((ext_vector_type(8))) __bf16 bf16x8;
typedef __attribute__((ext_vector_type(4))) __bf16 bf16x4;
typedef __attribute__((ext_vector_type(4))) float f32x4;
typedef __attribute__((ext_vector_type(4))) float f4;

static __device__ __forceinline__ f32x4 mfma_bf16(bf16x8 a, bf16x8 b, f32x4 c) {
  return __builtin_amdgcn_mfma_f32_16x16x32_bf16(a, b, c, 0, 0, 0);
}

static __device__ __forceinline__ uint32_t pack_bf16(float a, float b) {
  uint16_t ux = __builtin_bit_cast(uint16_t, (__bf16)a);
  uint16_t uy = __builtin_bit_cast(uint16_t, (__bf16)b);
  return (uint32_t)ux | ((uint32_t)uy << 16);
}

#define GLOAD_LDS16(gp, lp)                                                     \
  __builtin_amdgcn_global_load_lds(                                             \
      (const __attribute__((address_space(1))) uint32_t*)(gp),                  \
      (__attribute__((address_space(3))) uint32_t*)(lp), 16, 0, 0)

// ---- merged prep: blocks 0..143 = weight cvt (4 x 36), 144..527 = bias+mask ----
__global__ void prep(const float* __restrict__ q_w, const float* __restrict__ k_w,
                     const float* __restrict__ v_w, const float* __restrict__ p_w,
                     __bf16* __restrict__ wq, __bf16* __restrict__ wk,
                     __bf16* __restrict__ wv, __bf16* __restrict__ wp,
                     const float* __restrict__ maskp, const float* __restrict__ btab,
                     float* __restrict__ bmall) {
  const int bid = blockIdx.x;
  if (bid < 144) {
    const int y = bid / 36;
    const float* s = y == 0 ? q_w : y == 1 ? k_w : y == 2 ? v_w : p_w;
    __bf16* d = y == 0 ? wq : y == 1 ? wk : y == 2 ? wv : wp;
    int i = (bid % 36) * 256 + threadIdx.x;      // 9216 f4 groups per weight
    f4 v = ((const f4*)s)[i];
    bf16x4 b;
    b[0] = (__bf16)v[0]; b[1] = (__bf16)v[1]; b[2] = (__bf16)v[2]; b[3] = (__bf16)v[3];
    ((bf16x4*)d)[i] = b;
  } else {
    const int idx = bid - 144;                   // 384 = 64 win x 6 heads
    const int win = idx / 6, h = idx - win * 6;
    float* dst = bmall + ((size_t)idx) * 2800;
    for (int i = threadIdx.x; i < 2796; i += 256) {
      int q = i / 57, ke = i - q * 57;
      int k = ke >= 49 ? ke - 49 : ke;
      if (q > 48) q = 48;
      int qi = q / 7, qj = q - qi * 7, ki = k / 7, kj = k - ki * 7;
      int rel = (qi - ki + 6) * 13 + (qj - kj + 6);
      dst[i] = (maskp[win * 2401 + q * 49 + k] + btab[rel * 6 + h]) * L2E;
    }
  }
}

// ---- GEMM v11: r17 pipeline, tile size parameterized (occupancy experiment) ----
// RPT=16 for qkv: 3 x 12KB LDS = 36KB -> 4 blocks/CU x 4 waves = 16 waves/CU
// (VGPR ~110 stays in <=128 tier). Little's-law theory: achieved BW scales
// with resident waves (qkv 8 waves -> 3.5 TB/s vs attn 20 waves -> 5.6 TB/s).
template<bool IN_F32, bool OUT_F32, int RPT, int TILES>
static __device__ __forceinline__
void gemm_pipe(const void* __restrict__ Xv, const __bf16* __restrict__ Wb,
               const float* __restrict__ bias, void* __restrict__ Ov, float scale,
               char* Xs)
{
  constexpr int CPR = IN_F32 ? 48 : 24;          // 16B chunks per 192-elem row
  constexpr int LPW = RPT * CPR / 256;           // global_load_lds per thread/tile
  constexpr int TB  = RPT * CPR * 16;            // tile bytes
  constexpr int RG  = RPT / 16;                  // 16-row groups per tile
  constexpr int STEADY = RG * 12 + LPW;          // stores(prev tile) + stage(next)
  const int tid = threadIdx.x;
  const int wv = tid >> 6, lane = tid & 63, lr = lane & 15, lg = lane >> 4;
  const size_t blk0 = (size_t)blockIdx.x * (RPT * TILES);

  bf16x8 wf[3][6];
  float bcol[3];
  #pragma unroll
  for (int t = 0; t < 3; ++t) {
    const int nt = wv + 4 * t;
    const __bf16* wr = &Wb[(nt * 16 + lr) * 192 + lg * 8];
    #pragma unroll
    for (int kk = 0; kk < 6; ++kk) wf[t][kk] = *(const bf16x8*)&wr[kk * 32];
    bcol[t] = bias[nt * 16 + lr] * scale;
  }

  auto stage = [&](int buf, int t) {
    const size_t row0 = blk0 + (size_t)t * RPT;
    char* ldsb = Xs + buf * TB;
    int l = (wv * LPW) * 64 + lane;
    #pragma unroll
    for (int p = 0; p < LPW; ++p) {
      int r = l / CPR;
      int c16 = (l - r * CPR) ^ (r & 7);
      const char* src;
      if (IN_F32) {
        src = (const char*)Xv + ((row0 + r) * 768 + c16 * 16);
      } else {
        int hh = c16 >> 2, sub = c16 & 3;
        src = (const char*)Xv + (((size_t)hh * ROWS + row0 + r) * 64 + sub * 16);
      }
      GLOAD_LDS16(src, ldsb + (wv * LPW + p) * 1024);
      l += 64;
    }
  };

  stage(0, 0);
  stage(1, 1);

  #pragma unroll
  for (int it = 0; it < TILES; ++it) {
    if (it == 0) {
      asm volatile("s_waitcnt vmcnt(%0)" :: "i"(LPW) : "memory");
    } else if (it + 1 < TILES) {
      asm volatile("s_waitcnt vmcnt(%0)" :: "i"(STEADY) : "memory");
    } else {
      asm volatile("s_waitcnt vmcnt(0)" ::: "memory");
    }
    __builtin_amdgcn_s_barrier();                // raw: no compiler vmcnt(0) drain

    const size_t row0 = blk0 + (size_t)it * RPT;
    const char* cb = Xs + (it % 3) * TB;

    // A-fragments from LDS (swizzled reads), convert if f32
    bf16x8 a[RG][6];
    #pragma unroll
    for (int rg = 0; rg < RG; ++rg) {
      const int rr = rg * 16 + lr;
      const char* rb = cb + rr * (CPR * 16);
      const int sw = rr & 7;
      if (IN_F32) {
        #pragma unroll
        for (int kk = 0; kk < 6; ++kk) {
          const int g0 = kk * 8 + lg * 2;
          f4 lo = *(const f4*)(rb + ((g0 ^ sw) * 16));
          f4 hi = *(const f4*)(rb + (((g0 + 1) ^ sw) * 16));
          #pragma unroll
          for (int e = 0; e < 4; ++e) {
            a[rg][kk][e]     = (__bf16)lo[e];
            a[rg][kk][4 + e] = (__bf16)hi[e];
          }
        }
      } else {
        #pragma unroll
        for (int kk = 0; kk < 6; ++kk) {
          const int g = kk * 4 + lg;
          a[rg][kk] = *(const bf16x8*)(rb + ((g ^ sw) * 16));
        }
      }
    }

    // fire staging 2 tiles ahead (into the buffer read at iter it-1)
    if (it + 2 < TILES) stage((it + 2) % 3, it + 2);
    asm volatile("" ::: "memory");               // pin stage before stores

    // MFMA + store
    #pragma unroll
    for (int rg = 0; rg < RG; ++rg) {
      const size_t grow = row0 + rg * 16 + lg * 4;
      #pragma unroll
      for (int t = 0; t < 3; ++t) {
        f32x4 acc = {0.f, 0.f, 0.f, 0.f};
        #pragma unroll
        for (int kk = 0; kk < 6; ++kk) acc = mfma_bf16(a[rg][kk], wf[t][kk], acc);
        const int nt = wv + 4 * t;
        if (OUT_F32) {
          const int col = nt * 16 + lr;
          #pragma unroll
          for (int j = 0; j < 4; ++j)
            ((float*)Ov)[(grow + j) * 192 + col] = acc[j] * scale + bcol[t];
        } else {
          const int hh = nt >> 1, c32 = (nt & 1) * 16 + lr;
          #pragma unroll
          for (int j = 0; j < 4; ++j)
            ((__bf16*)Ov)[((size_t)hh * ROWS + grow + j) * 32 + c32] =
                (__bf16)(acc[j] * scale + bcol[t]);
        }
      }
    }
    asm volatile("" ::: "memory");               // pin stores before next wait
  }
}

// fused QKV: 16-row tiles x 8 = 128 rows/block; grid (1176, 3)
// Falsifier: occupancy ~20% / dur ~145 -> plateau is issue-rate, not occupancy.
__global__ __launch_bounds__(256, 2)
void qkvgemm(const float* __restrict__ xq, const float* __restrict__ xk,
             const float* __restrict__ xv,
             const __bf16* __restrict__ wq, const __bf16* __restrict__ wk,
             const __bf16* __restrict__ wv,
             const float* __restrict__ bq, const float* __restrict__ bk,
             const float* __restrict__ bv,
             __bf16* __restrict__ oq, __bf16* __restrict__ ok,
             __bf16* __restrict__ ov)
{
  __shared__ __align__(16) char Xs[3 * 12288];   // 36KB -> 4 blocks/CU
  const int y = blockIdx.y;
  const float* x = y == 0 ? xq : y == 1 ? xk : xv;
  const __bf16* w = y == 0 ? wq : y == 1 ? wk : wv;
  const float* bi = y == 0 ? bq : y == 1 ? bk : bv;
  __bf16* o = y == 0 ? oq : y == 1 ? ok : ov;
  const float scale = y == 0 ? (QSCALE * L2E) : 1.f;
  gemm_pipe<true, false, 16, 8>(x, w, bi, o, scale, Xs);
}

// proj: head-major bf16 in, row-major f32 out; 32-row tiles x 6; grid 784
__global__ __launch_bounds__(256, 2)
void projgemm(const __bf16* __restrict__ X, const __bf16* __restrict__ Wb,
              const float* __restrict__ bias, float* __restrict__ Ov)
{
  __shared__ __align__(16) char Xs[3 * 12288];   // 36KB
  gemm_pipe<false, true, 32, 6>(X, Wb, bias, Ov, 1.f, Xs);
}

// ---- attention v8 (round-10 proven, unchanged): head-major I/O, bm in LDS ----
__global__ __launch_bounds__(320, 5)
void attn8(const __bf16* __restrict__ Q, const __bf16* __restrict__ K,
           const __bf16* __restrict__ V, __bf16* __restrict__ O,
           const float* __restrict__ bmall)
{
  __shared__ __align__(16) __bf16 Ks[160 * 40];   // 12800 B, permuted rows
  __shared__ __align__(16) __bf16 Vt[32 * 168];   // 10752 B, [d][key pad168]
  __shared__ __align__(16) float bm2[2796];       // 11184 B, stride 57 (odd)

  const int b = blockIdx.x, h = blockIdx.y;
  const int tid = threadIdx.x;
  const size_t hb = (size_t)h * ROWS + (size_t)b * 147;  // head-major row base
  const int wv = tid >> 6, lane = tid & 63;
  const int lr = lane & 15, lg = lane >> 4;

  bf16x8 qf = *(const bf16x8*)&Q[(hb + wv * 16 + lr) * 32 + lg * 8];

  {
    const f4* bsrc = (const f4*)(bmall + (size_t)((b & 63) * 6 + h) * 2800);
    for (int i = tid; i < 699; i += 320) ((f4*)bm2)[i] = bsrc[i];
  }
  for (int i = tid; i < 588; i += 320) {          // K -> permuted rows
    int k = i >> 2, c = i & 3;
    int phys = (k & ~31) | (((k >> 2) & 1) << 4) | (((k >> 3) & 3) << 2) | (k & 3);
    *(bf16x8*)&Ks[phys * 40 + c * 8] = *(const bf16x8*)&K[(hb + k) * 32 + c * 8];
  }
  for (int t = tid; t < 588; t += 320) {          // V transpose scatter
    int key = t >> 2, dblk = t & 3;
    bf16x8 v = *(const bf16x8*)&V[(hb + key) * 32 + dblk * 8];
    #pragma unroll
    for (int e = 0; e < 8; ++e) Vt[(dblk * 8 + e) * 168 + key] = v[e];
  }
  for (int i = tid; i < 32 * 13; i += 320) {      // zero key tail 147..159
    int d = i / 13, key = 147 + (i - (i / 13) * 13);
    Vt[d * 168 + key] = (__bf16)0.f;
  }
  __syncthreads();

  #pragma unroll
  for (int t = 0; t < 2; ++t) {
    const int mt = wv + 5 * t;                     // waves cover mt 0..9 exactly

    bf16x8 qn = qf;
    if (t == 0) {
      int qr = (wv + 5) * 16 + lr; if (qr > 146) qr = 146;
      qn = *(const bf16x8*)&Q[(hb + qr) * 32 + lg * 8];
    }

    int r = mt * 16 + lr;
    int q49 = r; if (q49 >= 98) q49 -= 98; if (q49 >= 49) q49 -= 49;
    const float* bmrow = &bm2[q49 * 57];

    f32x4 o0 = {0.f,0.f,0.f,0.f}, o1 = {0.f,0.f,0.f,0.f};
    float sum = 0.f;
    int kb = lg * 8;                               // (32s + 8lg) % 49, incremental
    #pragma unroll
    for (int s = 0; s < 5; ++s) {
      const f32x4 z = {0.f,0.f,0.f,0.f};
      f32x4 st0 = mfma_bf16(*(const bf16x8*)&Ks[(s * 32 + lr) * 40 + lg * 8], qf, z);
      f32x4 st1 = mfma_bf16(*(const bf16x8*)&Ks[(s * 32 + 16 + lr) * 40 + lg * 8], qf, z);
      const float* bp = bmrow + kb;                // 8 consecutive f32 (row has 57)
      #pragma unroll
      for (int j = 0; j < 4; ++j) { st0[j] += bp[j]; st1[j] += bp[4 + j]; }
      if (s == 4) {                                // keys 128+8lg+j / 132+8lg+j >= 147
        #pragma unroll
        for (int j = 0; j < 4; ++j) {
          if (lg * 8 + j >= 19) st0[j] = -1e30f;
          if (lg * 8 + j >= 15) st1[j] = -1e30f;
        }
      }
      #pragma unroll
      for (int j = 0; j < 4; ++j) { st0[j] = exp2f(st0[j]); sum += st0[j]; }
      #pragma unroll
      for (int j = 0; j < 4; ++j) { st1[j] = exp2f(st1[j]); sum += st1[j]; }
      union { bf16x8 v; uint32_t w[4]; } pu;
      pu.w[0] = pack_bf16(st0[0], st0[1]);
      pu.w[1] = pack_bf16(st0[2], st0[3]);
      pu.w[2] = pack_bf16(st1[0], st1[1]);
      pu.w[3] = pack_bf16(st1[2], st1[3]);
      bf16x8 v0 = *(const bf16x8*)&Vt[lr * 168 + s * 32 + lg * 8];
      bf16x8 v1 = *(const bf16x8*)&Vt[(16 + lr) * 168 + s * 32 + lg * 8];
      o0 = mfma_bf16(pu.v, v0, o0);
      o1 = mfma_bf16(pu.v, v1, o1);
      kb += 32; if (kb >= 49) kb -= 49;            // stays in [0,49)
    }
    sum += __shfl_xor(sum, 16);
    sum += __shfl_xor(sum, 32);
    const float rinv = 1.f / sum;
    #pragma unroll
    for (int j = 0; j < 4; ++j) {
      const int qa = mt * 16 + lg * 4 + j;
      const float rj = __shfl(rinv, lg * 4 + j);   // row sums live at lanes 0..15
      if (qa < 147) {
        const size_t base = (hb + qa) * 32;
        O[base + lr]      = (__bf16)(o0[j] * rj);
        O[base + 16 + lr] = (__bf16)(o1[j] * rj);
      }
    }
    qf = qn;
  }
}

extern "C" void kernel_launch(void* const* d_in, const int* in_sizes, int n_in,
                              void* d_out, int out_size, void* d_ws, size_t ws_size,
                              hipStream_t stream) {
  (void)in_sizes; (void)n_in; (void)out_size;
  const float* x_q  = (const float*)d_in[0];
  const float* x_k  = (const float*)d_in[1];
  const float* x_v  = (const float*)d_in[2];
  const float* maskp= (const float*)d_in[3];
  const float* q_w  = (const float*)d_in[4];
  const float* q_b  = (const float*)d_in[5];
  const float* k_w  = (const float*)d_in[6];
  const float* k_b  = (const float*)d_in[7];
  const float* v_w  = (const float*)d_in[8];
  const float* v_b  = (const float*)d_in[9];
  const float* p_w  = (const float*)d_in[10];
  const float* p_b  = (const float*)d_in[11];
  const float* btab = (const float*)d_in[12];

  char* ws = (char*)d_ws;
  // [bmall 4.3MB][4 weights][qb][kb][vb][ob?]
  float* bmall = (float*)ws;
  const size_t bmsz = (size_t)64 * 6 * 2800 * sizeof(float);   // 4,300,800
  char* wsp = ws + bmsz;
  const size_t wsz = 36864 * sizeof(__bf16);
  __bf16* wq  = (__bf16*)wsp;
  __bf16* wk  = (__bf16*)(wsp + wsz);
  __bf16* wvp = (__bf16*)(wsp + 2 * wsz);
  __bf16* wp  = (__bf16*)(wsp + 3 * wsz);
  char* bufs = wsp + 4 * wsz;
  const size_t sz = (size_t)ROWS * 192 * sizeof(__bf16);       // 57.8 MB each
  __bf16* qb = (__bf16*)bufs;
  __bf16* kb = (__bf16*)(bufs + sz);
  __bf16* vb = (__bf16*)(bufs + 2 * sz);
  const size_t need4 = bmsz + 4 * wsz + 4 * sz;
  __bf16* ob = (ws_size >= need4) ? (__bf16*)(bufs + 3 * sz) : qb;

  prep<<<528, 256, 0, stream>>>(q_w, k_w, v_w, p_w, wq, wk, wvp, wp,
                                maskp, btab, bmall);

  // q pre-scaled by 1/sqrt(hd) AND log2(e) (exp2-direct softmax downstream)
  qkvgemm<<<dim3(ROWS / 128, 3), 256, 0, stream>>>(x_q, x_k, x_v, wq, wk, wvp,
                                                   q_b, k_b, v_b, qb, kb, vb);

  attn8<<<dim3(1024, 6), 320, 0, stream>>>(qb, kb, vb, ob, bmall);

  projgemm<<<ROWS / 192, 256, 0, stream>>>(ob, wp, p_b, (float*)d_out);
}

// Round 19
// 260.349 us; speedup vs baseline: 1.0051x; 1.0051x over previous
//
#include <hip/hip_runtime.h>
#include <stdint.h>

#define ROWS 150528              // 1024 * 147
#define QSCALE 0.17677669529663687f
#define L2E 1.44269504088896f

typedef __attribute__((ext_vector_type(8))) __bf16 bf16x8;
typedef __attribute__((ext_vector_type(4))) __bf16 bf16x4;
typedef __attribute__((ext_vector_type(4))) float f32x4;
typedef __attribute__((ext_vector_type(4))) float f4;
typedef __attribute__((ext_vector_type(2))) uint32_t u32x2;

static __device__ __forceinline__ f32x4 mfma_bf16(bf16x8 a, bf16x8 b, f32x4 c) {
  return __builtin_amdgcn_mfma_f32_16x16x32_bf16(a, b, c, 0, 0, 0);
}

static __device__ __forceinline__ uint32_t pack_bf16(float a, float b) {
  uint16_t ux = __builtin_bit_cast(uint16_t, (__bf16)a);
  uint16_t uy = __builtin_bit_cast(uint16_t, (__bf16)b);
  return (uint32_t)ux | ((uint32_t)uy << 16);
}

#define GLOAD_LDS16(gp, lp)                                                     \
  __builtin_amdgcn_global_load_lds(                                             \
      (const __attribute__((address_space(1))) uint32_t*)(gp),                  \
      (__attribute__((address_space(3))) uint32_t*)(lp), 16, 0, 0)

// ---- merged prep: blocks 0..143 = weight cvt (4 x 36), 144..527 = bias+mask ----
__global__ void prep(const float* __restrict__ q_w, const float* __restrict__ k_w,
                     const float* __restrict__ v_w, const float* __restrict__ p_w,
                     __bf16* __restrict__ wq, __bf16* __restrict__ wk,
                     __bf16* __restrict__ wv, __bf16* __restrict__ wp,
                     const float* __restrict__ maskp, const float* __restrict__ btab,
                     float* __restrict__ bmall) {
  const int bid = blockIdx.x;
  if (bid < 144) {
    const int y = bid / 36;
    const float* s = y == 0 ? q_w : y == 1 ? k_w : y == 2 ? v_w : p_w;
    __bf16* d = y == 0 ? wq : y == 1 ? wk : y == 2 ? wv : wp;
    int i = (bid % 36) * 256 + threadIdx.x;      // 9216 f4 groups per weight
    f4 v = ((const f4*)s)[i];
    bf16x4 b;
    b[0] = (__bf16)v[0]; b[1] = (__bf16)v[1]; b[2] = (__bf16)v[2]; b[3] = (__bf16)v[3];
    ((bf16x4*)d)[i] = b;
  } else {
    const int idx = bid - 144;                   // 384 = 64 win x 6 heads
    const int win = idx / 6, h = idx - win * 6;
    float* dst = bmall + ((size_t)idx) * 2800;
    for (int i = threadIdx.x; i < 2796; i += 256) {
      int q = i / 57, ke = i - q * 57;
      int k = ke >= 49 ? ke - 49 : ke;
      if (q > 48) q = 48;
      int qi = q / 7, qj = q - qi * 7, ki = k / 7, kj = k - ki * 7;
      int rel = (qi - ki + 6) * 13 + (qj - kj + 6);
      dst[i] = (maskp[win * 2401 + q * 49 + k] + btab[rel * 6 + h]) * L2E;
    }
  }
}

// ---- GEMM v12: r18 pipeline + SWAPPED-MFMA dense stores + loose vmcnt ----
// mfma(wf, a) yields C^T layout: lane (lr,lg) holds C[row=row0+rg*16+lr]
// [cols nt*16+4lg..+3] -> ONE 8B (bf16) / 16B (f32) dense store per t
// (was 4 scattered 2B/4B stores). vmcnt schedule only requires the CURRENT
// tile's stage loads retired -- store-acks may lag 2 full iterations
// (old STEADY=SPT+LPW forced stores(it-2) acked -> suspected serializer).
template<bool IN_F32, bool OUT_F32, int RPT, int TILES>
static __device__ __forceinline__
void gemm_pipe(const void* __restrict__ Xv, const __bf16* __restrict__ Wb,
               const float* __restrict__ bias, void* __restrict__ Ov, float scale,
               char* Xs, int bx)
{
  constexpr int CPR = IN_F32 ? 48 : 24;          // 16B chunks per 192-elem row
  constexpr int LPW = RPT * CPR / 256;           // global_load_lds per thread/tile
  constexpr int TB  = RPT * CPR * 16;            // tile bytes
  constexpr int RG  = RPT / 16;                  // 16-row groups per tile
  constexpr int SPT = RG * 3;                    // stores per thread per tile
  const int tid = threadIdx.x;
  const int wv = tid >> 6, lane = tid & 63, lr = lane & 15, lg = lane >> 4;
  const size_t blk0 = (size_t)bx * (RPT * TILES);

  bf16x8 wf[3][6];
  f4 bc4[3];
  #pragma unroll
  for (int t = 0; t < 3; ++t) {
    const int nt = wv + 4 * t;
    const __bf16* wr = &Wb[(nt * 16 + lr) * 192 + lg * 8];
    #pragma unroll
    for (int kk = 0; kk < 6; ++kk) wf[t][kk] = *(const bf16x8*)&wr[kk * 32];
    f4 bb = *(const f4*)&bias[nt * 16 + 4 * lg];
    #pragma unroll
    for (int e = 0; e < 4; ++e) bc4[t][e] = bb[e] * scale;
  }

  auto stage = [&](int buf, int t) {
    const size_t row0 = blk0 + (size_t)t * RPT;
    char* ldsb = Xs + buf * TB;
    int l = (wv * LPW) * 64 + lane;
    #pragma unroll
    for (int p = 0; p < LPW; ++p) {
      int r = l / CPR;
      int c16 = (l - r * CPR) ^ (r & 7);
      const char* src;
      if (IN_F32) {
        src = (const char*)Xv + ((row0 + r) * 768 + c16 * 16);
      } else {
        int hh = c16 >> 2, sub = c16 & 3;
        src = (const char*)Xv + (((size_t)hh * ROWS + row0 + r) * 64 + sub * 16);
      }
      GLOAD_LDS16(src, ldsb + (wv * LPW + p) * 1024);
      l += 64;
    }
  };

  stage(0, 0);
  stage(1, 1);

  #pragma unroll
  for (int it = 0; it < TILES; ++it) {
    // wait ONLY for tile it's stage loads (derived per-phase exact counts)
    if (it == 0) {
      asm volatile("s_waitcnt vmcnt(%0)" :: "i"(LPW) : "memory");
    } else if (it == 1) {
      asm volatile("s_waitcnt vmcnt(%0)" :: "i"(SPT + LPW) : "memory");
    } else if (it + 1 < TILES) {
      asm volatile("s_waitcnt vmcnt(%0)" :: "i"(2 * SPT + LPW) : "memory");
    } else {
      asm volatile("s_waitcnt vmcnt(%0)" :: "i"(2 * SPT) : "memory");
    }
    __builtin_amdgcn_s_barrier();                // raw: no compiler vmcnt(0) drain

    const size_t row0 = blk0 + (size_t)it * RPT;
    const char* cb = Xs + (it % 3) * TB;

    // A-fragments from LDS (swizzled reads), convert if f32
    bf16x8 a[RG][6];
    #pragma unroll
    for (int rg = 0; rg < RG; ++rg) {
      const int rr = rg * 16 + lr;
      const char* rb = cb + rr * (CPR * 16);
      const int sw = rr & 7;
      if (IN_F32) {
        #pragma unroll
        for (int kk = 0; kk < 6; ++kk) {
          const int g0 = kk * 8 + lg * 2;
          f4 lo = *(const f4*)(rb + ((g0 ^ sw) * 16));
          f4 hi = *(const f4*)(rb + (((g0 + 1) ^ sw) * 16));
          #pragma unroll
          for (int e = 0; e < 4; ++e) {
            a[rg][kk][e]     = (__bf16)lo[e];
            a[rg][kk][4 + e] = (__bf16)hi[e];
          }
        }
      } else {
        #pragma unroll
        for (int kk = 0; kk < 6; ++kk) {
          const int g = kk * 4 + lg;
          a[rg][kk] = *(const bf16x8*)(rb + ((g ^ sw) * 16));
        }
      }
    }

    // fire staging 2 tiles ahead (into the buffer read at iter it-1)
    if (it + 2 < TILES) stage((it + 2) % 3, it + 2);
    asm volatile("" ::: "memory");               // pin stage before stores

    // swapped MFMA (C^T layout) + dense stores
    #pragma unroll
    for (int rg = 0; rg < RG; ++rg) {
      const size_t grow = row0 + rg * 16 + lr;   // this lane's OUTPUT ROW
      #pragma unroll
      for (int t = 0; t < 3; ++t) {
        f32x4 acc = {0.f, 0.f, 0.f, 0.f};
        #pragma unroll
        for (int kk = 0; kk < 6; ++kk) acc = mfma_bf16(wf[t][kk], a[rg][kk], acc);
        const int nt = wv + 4 * t;
        if (OUT_F32) {
          f4 ov;
          #pragma unroll
          for (int j = 0; j < 4; ++j) ov[j] = acc[j] * scale + bc4[t][j];
          *(f4*)&((float*)Ov)[grow * 192 + nt * 16 + 4 * lg] = ov;
        } else {
          u32x2 pw;
          pw[0] = pack_bf16(acc[0] * scale + bc4[t][0], acc[1] * scale + bc4[t][1]);
          pw[1] = pack_bf16(acc[2] * scale + bc4[t][2], acc[3] * scale + bc4[t][3]);
          const int hh = nt >> 1;
          *(u32x2*)&((__bf16*)Ov)[((size_t)hh * ROWS + grow) * 32 +
                                  (nt & 1) * 16 + 4 * lg] = pw;
        }
      }
    }
    asm volatile("" ::: "memory");               // pin stores before next wait
  }
}

// fused QKV: 16-row tiles x 8 = 128 rows/block; grid (1176, 3); XCD-swizzled
__global__ __launch_bounds__(256, 2)
void qkvgemm(const float* __restrict__ xq, const float* __restrict__ xk,
             const float* __restrict__ xv,
             const __bf16* __restrict__ wq, const __bf16* __restrict__ wk,
             const __bf16* __restrict__ wv,
             const float* __restrict__ bq, const float* __restrict__ bk,
             const float* __restrict__ bv,
             __bf16* __restrict__ oq, __bf16* __restrict__ ok,
             __bf16* __restrict__ ov)
{
  __shared__ __align__(16) char Xs[3 * 12288];   // 36KB -> 4 blocks/CU
  const int y = blockIdx.y;
  const int bx = (blockIdx.x & 7) * 147 + (blockIdx.x >> 3);   // 1176 = 8*147
  const float* x = y == 0 ? xq : y == 1 ? xk : xv;
  const __bf16* w = y == 0 ? wq : y == 1 ? wk : wv;
  const float* bi = y == 0 ? bq : y == 1 ? bk : bv;
  __bf16* o = y == 0 ? oq : y == 1 ? ok : ov;
  const float scale = y == 0 ? (QSCALE * L2E) : 1.f;
  gemm_pipe<true, false, 16, 8>(x, w, bi, o, scale, Xs, bx);
}

// proj: head-major bf16 in, row-major f32 out; 32-row tiles x 6; grid 784
__global__ __launch_bounds__(256, 2)
void projgemm(const __bf16* __restrict__ X, const __bf16* __restrict__ Wb,
              const float* __restrict__ bias, float* __restrict__ Ov)
{
  __shared__ __align__(16) char Xs[3 * 12288];   // 36KB
  const int bx = (blockIdx.x & 7) * 98 + (blockIdx.x >> 3);    // 784 = 8*98
  gemm_pipe<false, true, 32, 6>(X, Wb, bias, Ov, 1.f, Xs, bx);
}

// ---- attention v8 (round-10 proven): head-major I/O, bm in LDS, XCD swizzle ----
__global__ __launch_bounds__(320, 5)
void attn8(const __bf16* __restrict__ Q, const __bf16* __restrict__ K,
           const __bf16* __restrict__ V, __bf16* __restrict__ O,
           const float* __restrict__ bmall)
{
  __shared__ __align__(16) __bf16 Ks[160 * 40];   // 12800 B, permuted rows
  __shared__ __align__(16) __bf16 Vt[32 * 168];   // 10752 B, [d][key pad168]
  __shared__ __align__(16) float bm2[2796];       // 11184 B, stride 57 (odd)

  const int b = (blockIdx.x & 7) * 128 + (blockIdx.x >> 3);    // 1024 = 8*128
  const int h = blockIdx.y;
  const int tid = threadIdx.x;
  const size_t hb = (size_t)h * ROWS + (size_t)b * 147;  // head-major row base
  const int wv = tid >> 6, lane = tid & 63;
  const int lr = lane & 15, lg = lane >> 4;

  bf16x8 qf = *(const bf16x8*)&Q[(hb + wv * 16 + lr) * 32 + lg * 8];

  {
    const f4* bsrc = (const f4*)(bmall + (size_t)((b & 63) * 6 + h) * 2800);
    for (int i = tid; i < 699; i += 320) ((f4*)bm2)[i] = bsrc[i];
  }
  for (int i = tid; i < 588; i += 320) {          // K -> permuted rows
    int k = i >> 2, c = i & 3;
    int phys = (k & ~31) | (((k >> 2) & 1) << 4) | (((k >> 3) & 3) << 2) | (k & 3);
    *(bf16x8*)&Ks[phys * 40 + c * 8] = *(const bf16x8*)&K[(hb + k) * 32 + c * 8];
  }
  for (int t = tid; t < 588; t += 320) {          // V transpose scatter
    int key = t >> 2, dblk = t & 3;
    bf16x8 v = *(const bf16x8*)&V[(hb + key) * 32 + dblk * 8];
    #pragma unroll
    for (int e = 0; e < 8; ++e) Vt[(dblk * 8 + e) * 168 + key] = v[e];
  }
  for (int i = tid; i < 32 * 13; i += 320) {      // zero key tail 147..159
    int d = i / 13, key = 147 + (i - (i / 13) * 13);
    Vt[d * 168 + key] = (__bf16)0.f;
  }
  __syncthreads();

  #pragma unroll
  for (int t = 0; t < 2; ++t) {
    const int mt = wv + 5 * t;                     // waves cover mt 0..9 exactly

    bf16x8 qn = qf;
    if (t == 0) {
      int qr = (wv + 5) * 16 + lr; if (qr > 146) qr = 146;
      qn = *(const bf16x8*)&Q[(hb + qr) * 32 + lg * 8];
    }

    int r = mt * 16 + lr;
    int q49 = r; if (q49 >= 98) q49 -= 98; if (q49 >= 49) q49 -= 49;
    const float* bmrow = &bm2[q49 * 57];

    f32x4 o0 = {0.f,0.f,0.f,0.f}, o1 = {0.f,0.f,0.f,0.f};
    float sum = 0.f;
    int kb = lg * 8;                               // (32s + 8lg) % 49, incremental
    #pragma unroll
    for (int s = 0; s < 5; ++s) {
      const f32x4 z = {0.f,0.f,0.f,0.f};
      f32x4 st0 = mfma_bf16(*(const bf16x8*)&Ks[(s * 32 + lr) * 40 + lg * 8], qf, z);
      f32x4 st1 = mfma_bf16(*(const bf16x8*)&Ks[(s * 32 + 16 + lr) * 40 + lg * 8], qf, z);
      const float* bp = bmrow + kb;                // 8 consecutive f32 (row has 57)
      #pragma unroll
      for (int j = 0; j < 4; ++j) { st0[j] += bp[j]; st1[j] += bp[4 + j]; }
      if (s == 4) {                                // keys 128+8lg+j / 132+8lg+j >= 147
        #pragma unroll
        for (int j = 0; j < 4; ++j) {
          if (lg * 8 + j >= 19) st0[j] = -1e30f;
          if (lg * 8 + j >= 15) st1[j] = -1e30f;
        }
      }
      #pragma unroll
      for (int j = 0; j < 4; ++j) { st0[j] = exp2f(st0[j]); sum += st0[j]; }
      #pragma unroll
      for (int j = 0; j < 4; ++j) { st1[j] = exp2f(st1[j]); sum += st1[j]; }
      union { bf16x8 v; uint32_t w[4]; } pu;
      pu.w[0] = pack_bf16(st0[0], st0[1]);
      pu.w[1] = pack_bf16(st0[2], st0[3]);
      pu.w[2] = pack_bf16(st1[0], st1[1]);
      pu.w[3] = pack_bf16(st1[2], st1[3]);
      bf16x8 v0 = *(const bf16x8*)&Vt[lr * 168 + s * 32 + lg * 8];
      bf16x8 v1 = *(const bf16x8*)&Vt[(16 + lr) * 168 + s * 32 + lg * 8];
      o0 = mfma_bf16(pu.v, v0, o0);
      o1 = mfma_bf16(pu.v, v1, o1);
      kb += 32; if (kb >= 49) kb -= 49;            // stays in [0,49)
    }
    sum += __shfl_xor(sum, 16);
    sum += __shfl_xor(sum, 32);
    const float rinv = 1.f / sum;
    #pragma unroll
    for (int j = 0; j < 4; ++j) {
      const int qa = mt * 16 + lg * 4 + j;
      const float rj = __shfl(rinv, lg * 4 + j);   // row sums live at lanes 0..15
      if (qa < 147) {
        const size_t base = (hb + qa) * 32;
        O[base + lr]      = (__bf16)(o0[j] * rj);
        O[base + 16 + lr] = (__bf16)(o1[j] * rj);
      }
    }
    qf = qn;
  }
}

extern "C" void kernel_launch(void* const* d_in, const int* in_sizes, int n_in,
                              void* d_out, int out_size, void* d_ws, size_t ws_size,
                              hipStream_t stream) {
  (void)in_sizes; (void)n_in; (void)out_size;
  const float* x_q  = (const float*)d_in[0];
  const float* x_k  = (const float*)d_in[1];
  const float* x_v  = (const float*)d_in[2];
  const float* maskp= (const float*)d_in[3];
  const float* q_w  = (const float*)d_in[4];
  const float* q_b  = (const float*)d_in[5];
  const float* k_w  = (const float*)d_in[6];
  const float* k_b  = (const float*)d_in[7];
  const float* v_w  = (const float*)d_in[8];
  const float* v_b  = (const float*)d_in[9];
  const float* p_w  = (const float*)d_in[10];
  const float* p_b  = (const float*)d_in[11];
  const float* btab = (const float*)d_in[12];

  char* ws = (char*)d_ws;
  // [bmall 4.3MB][4 weights][qb][kb][vb][ob?]
  float* bmall = (float*)ws;
  const size_t bmsz = (size_t)64 * 6 * 2800 * sizeof(float);   // 4,300,800
  char* wsp = ws + bmsz;
  const size_t wsz = 36864 * sizeof(__bf16);
  __bf16* wq  = (__bf16*)wsp;
  __bf16* wk  = (__bf16*)(wsp + wsz);
  __bf16* wvp = (__bf16*)(wsp + 2 * wsz);
  __bf16* wp  = (__bf16*)(wsp + 3 * wsz);
  char* bufs = wsp + 4 * wsz;
  const size_t sz = (size_t)ROWS * 192 * sizeof(__bf16);       // 57.8 MB each
  __bf16* qb = (__bf16*)bufs;
  __bf16* kb = (__bf16*)(bufs + sz);
  __bf16* vb = (__bf16*)(bufs + 2 * sz);
  const size_t need4 = bmsz + 4 * wsz + 4 * sz;
  __bf16* ob = (ws_size >= need4) ? (__bf16*)(bufs + 3 * sz) : qb;

  prep<<<528, 256, 0, stream>>>(q_w, k_w, v_w, p_w, wq, wk, wvp, wp,
                                maskp, btab, bmall);

  // q pre-scaled by 1/sqrt(hd) AND log2(e) (exp2-direct softmax downstream)
  qkvgemm<<<dim3(ROWS / 128, 3), 256, 0, stream>>>(x_q, x_k, x_v, wq, wk, wvp,
                                                   q_b, k_b, v_b, qb, kb, vb);

  attn8<<<dim3(1024, 6), 320, 0, stream>>>(qb, kb, vb, ob, bmall);

  projgemm<<<ROWS / 192, 256, 0, stream>>>(ob, wp, p_b, (float*)d_out);
}